// Round 1
// baseline (108.327 us; speedup 1.0000x reference)
//
#include <hip/hip_runtime.h>
#include <math.h>

#define NH 512
#define NO 512
#define BT_TOT 256
#define HID 64
#define OUTD 128

__global__ __launch_bounds__(512) void interaction_encoder_kernel(
    const float* __restrict__ h_in,   // [BT, NH, 3]
    const float* __restrict__ o_in,   // [BT, NO, 3]
    const float* __restrict__ sh_in,  // [BT, NH]
    const float* __restrict__ W1,     // [10, 64]
    const float* __restrict__ b1,     // [64]
    const float* __restrict__ W2,     // [64, 128]
    const float* __restrict__ b2,     // [128]
    float* __restrict__ out)          // [BT, 128]
{
    __shared__ float hx[NH], hy[NH], hz[NH];
    __shared__ float ox[NO], oy[NO], oz[NO];
    __shared__ float dmin[NH];
    __shared__ float4 red[512];
    __shared__ float feats[16];
    __shared__ float hidden[HID];

    const int bt = blockIdx.x;
    const int t  = threadIdx.x;

    // ---- stage point clouds into LDS (coalesced global reads) ----
    const float* hsrc = h_in + (size_t)bt * NH * 3;
    const float* osrc = o_in + (size_t)bt * NO * 3;
    for (int idx = t; idx < NH * 3; idx += 512) {
        float v = hsrc[idx];
        int pt = idx / 3, c = idx - pt * 3;
        if (c == 0) hx[pt] = v; else if (c == 1) hy[pt] = v; else hz[pt] = v;
    }
    for (int idx = t; idx < NO * 3; idx += 512) {
        float v = osrc[idx];
        int pt = idx / 3, c = idx - pt * 3;
        if (c == 0) ox[pt] = v; else if (c == 1) oy[pt] = v; else oz[pt] = v;
    }
    __syncthreads();

    // ---- pass 1: per-human min/argmin over objects (4-way ILP) ----
    const float px = hx[t], py = hy[t], pz = hz[t];
    float best0 = 1e30f, best1 = 1e30f, best2 = 1e30f, best3 = 1e30f;
    int   bm0 = 0, bm1 = 1, bm2 = 2, bm3 = 3;
    for (int m = 0; m < NO; m += 4) {
        {
            float dx = ox[m] - px, dy = oy[m] - py, dz = oz[m] - pz;
            float d2 = dx * dx + dy * dy + dz * dz;
            if (d2 < best0) { best0 = d2; bm0 = m; }
        }
        {
            float dx = ox[m+1] - px, dy = oy[m+1] - py, dz = oz[m+1] - pz;
            float d2 = dx * dx + dy * dy + dz * dz;
            if (d2 < best1) { best1 = d2; bm1 = m + 1; }
        }
        {
            float dx = ox[m+2] - px, dy = oy[m+2] - py, dz = oz[m+2] - pz;
            float d2 = dx * dx + dy * dy + dz * dz;
            if (d2 < best2) { best2 = d2; bm2 = m + 2; }
        }
        {
            float dx = ox[m+3] - px, dy = oy[m+3] - py, dz = oz[m+3] - pz;
            float d2 = dx * dx + dy * dy + dz * dz;
            if (d2 < best3) { best3 = d2; bm3 = m + 3; }
        }
    }
    // combine with first-index tie-break (tracker i covers m ≡ i mod 4)
    float best = best0; int bm = bm0;
    if (best1 < best || (best1 == best && bm1 < bm)) { best = best1; bm = bm1; }
    if (best2 < best || (best2 == best && bm2 < bm)) { best = best2; bm = bm2; }
    if (best3 < best || (best3 == best && bm3 < bm)) { best = best3; bm = bm3; }

    const float dmin_t = sqrtf(best);
    // dir_h2o: vec = o[bm] - h[t]; ||vec||^2 == best exactly (same arithmetic)
    const float vx = ox[bm] - px, vy = oy[bm] - py, vz = oz[bm] - pz;
    const float inv = 1.0f / sqrtf(fmaxf(best, 1e-6f));
    const float dirx = vx * inv, diry = vy * inv, dirz = vz * inv;
    const float w_t = expf(-dmin_t / 0.05f) * sh_in[(size_t)bt * NH + t];

    dmin[t] = dmin_t;

    // ---- reduce A: {w, dirx, diry, dirz} ----
    red[t] = make_float4(w_t, dirx, diry, dirz);
    __syncthreads();
    for (int s = 256; s > 0; s >>= 1) {
        if (t < s) {
            float4 a = red[t], b = red[t + s];
            red[t] = make_float4(a.x + b.x, a.y + b.y, a.z + b.z, a.w + b.w);
        }
        __syncthreads();
    }
    if (t == 0) {
        float4 r = red[0];
        feats[5] = r.x * (1.0f / NH);
        feats[6] = r.y * (1.0f / NH);
        feats[7] = r.z * (1.0f / NH);
        feats[8] = r.w * (1.0f / NH);
    }

    // ---- bitonic sort dmin ascending (512 elems, 512 threads) ----
    for (int k2 = 2; k2 <= 512; k2 <<= 1) {
        for (int j = k2 >> 1; j > 0; j >>= 1) {
            __syncthreads();
            int ixj = t ^ j;
            if (ixj > t) {
                float a = dmin[t], b = dmin[ixj];
                bool swap = ((t & k2) == 0) ? (a > b) : (a < b);
                if (swap) { dmin[t] = b; dmin[ixj] = a; }
            }
        }
    }
    __syncthreads();

    // ---- reduce B: prefix sums {102, 256, 410, 512} smallest ----
    {
        float v = dmin[t];
        red[t] = make_float4(t < 102 ? v : 0.0f,
                             t < 256 ? v : 0.0f,
                             t < 410 ? v : 0.0f,
                             v);
    }
    __syncthreads();
    for (int s = 256; s > 0; s >>= 1) {
        if (t < s) {
            float4 a = red[t], b = red[t + s];
            red[t] = make_float4(a.x + b.x, a.y + b.y, a.z + b.z, a.w + b.w);
        }
        __syncthreads();
    }
    if (t == 0) {
        float4 r = red[0];
        feats[2] = r.x * (1.0f / 102.0f);
        feats[3] = r.y * (1.0f / 256.0f);
        feats[4] = r.z * (1.0f / 410.0f);
        feats[0] = r.w * (1.0f / NH);
        feats[1] = dmin[0];  // sorted min
    }

    // ---- pass 2: per-object min over humans (4-way ILP, min only) ----
    {
        const float qx = ox[t], qy = oy[t], qz = oz[t];
        float c0 = 1e30f, c1 = 1e30f, c2 = 1e30f, c3 = 1e30f;
        for (int n = 0; n < NH; n += 4) {
            {
                float dx = hx[n] - qx, dy = hy[n] - qy, dz = hz[n] - qz;
                c0 = fminf(c0, dx * dx + dy * dy + dz * dz);
            }
            {
                float dx = hx[n+1] - qx, dy = hy[n+1] - qy, dz = hz[n+1] - qz;
                c1 = fminf(c1, dx * dx + dy * dy + dz * dz);
            }
            {
                float dx = hx[n+2] - qx, dy = hy[n+2] - qy, dz = hz[n+2] - qz;
                c2 = fminf(c2, dx * dx + dy * dy + dz * dz);
            }
            {
                float dx = hx[n+3] - qx, dy = hy[n+3] - qy, dz = hz[n+3] - qz;
                c3 = fminf(c3, dx * dx + dy * dy + dz * dz);
            }
        }
        float dmo = sqrtf(fminf(fminf(c0, c1), fminf(c2, c3)));
        red[t] = make_float4(dmo, 0.0f, 0.0f, 0.0f);
    }
    __syncthreads();
    for (int s = 256; s > 0; s >>= 1) {
        if (t < s) red[t].x += red[t + s].x;
        __syncthreads();
    }
    if (t == 0) feats[9] = red[0].x * (1.0f / NO);
    __syncthreads();

    // ---- fused MLP: 10 -> 64 (ReLU) -> 128 ----
    if (t < HID) {
        float acc = b1[t];
        #pragma unroll
        for (int i = 0; i < 10; i++) acc += feats[i] * W1[i * HID + t];
        hidden[t] = fmaxf(acc, 0.0f);
    }
    __syncthreads();
    if (t < OUTD) {
        float acc = b2[t];
        #pragma unroll
        for (int j = 0; j < HID; j++) acc += hidden[j] * W2[j * OUTD + t];
        out[(size_t)bt * OUTD + t] = acc;
    }
}

extern "C" void kernel_launch(void* const* d_in, const int* in_sizes, int n_in,
                              void* d_out, int out_size, void* d_ws, size_t ws_size,
                              hipStream_t stream) {
    (void)in_sizes; (void)n_in; (void)out_size; (void)d_ws; (void)ws_size;
    const float* h_in  = (const float*)d_in[0];
    const float* o_in  = (const float*)d_in[1];
    const float* sh_in = (const float*)d_in[2];
    // d_in[3] (s_o) is dead code after the [:, :10] slice
    const float* W1 = (const float*)d_in[4];
    const float* b1 = (const float*)d_in[5];
    const float* W2 = (const float*)d_in[6];
    const float* b2 = (const float*)d_in[7];
    float* out = (float*)d_out;

    interaction_encoder_kernel<<<BT_TOT, 512, 0, stream>>>(
        h_in, o_in, sh_in, W1, b1, W2, b2, out);
}